// Round 5
// baseline (715.855 us; speedup 1.0000x reference)
//
#include <hip/hip_runtime.h>

// Problem constants
#define NROWS 8192   // rows of x / out
#define IN_F  4096   // K
#define OUT_F 4096   // output features
#define NPART 2048   // partial slots for w stats (= persistent grid size)

typedef __attribute__((ext_vector_type(4))) int i32x4;

// ---------------------------------------------------------------------------
// Static device scratch. Fully rewritten on every kernel_launch call.
// ---------------------------------------------------------------------------
__device__ double g_wsum_p[NPART];                  // per-block sum|w| (fp64)
__device__ float  g_sx[NROWS];                      // per-row x scale = rowmax/127
__device__ signed char g_wq[(size_t)OUT_F * IN_F];  // 16 MiB ternary i8
__device__ signed char g_xq[(size_t)NROWS * IN_F];  // 32 MiB x in i8
__device__ unsigned g_done = 0;  // phase-A completion counter (self-resetting)
__device__ unsigned g_fin  = 0;  // kernel completion counter  (self-resetting)

// ---------------------------------------------------------------------------
// Kernel 1 (persistent, ALL pre-GEMM work in one launch):
//   grid = 2048 blocks x 256 thr, __launch_bounds__(256,8) => 8 blocks/CU on
//   256 CUs = all blocks CO-RESIDENT (spin is deadlock-free by construction).
//   Phase A: per-block partial sum|w| (fp64), publish via threadfence +
//            release atomicAdd(g_done).
//   Phase B: x per-row quantization, 4 rows/block, row in registers,
//            per-row scale (factors out of the integer dot product exactly).
//            Long independent work that hides phase-A completion latency.
//   Phase C: acquire-spin until g_done == 2048 (by now ~instant).
//   Phase D: every block reduces the 2048 partials (L2-resident) to the
//            identical threshold, then grid-stride w -> ternary i8.
//   Counters self-reset by the last finishing block (no host memset needed;
//   visibility across replays via kernel-boundary release/acquire).
// ---------------------------------------------------------------------------
__global__ __launch_bounds__(256, 8) void tl_prep(const float* __restrict__ x,
                                                  const float* __restrict__ w) {
    const int tid = threadIdx.x;
    const int bid = blockIdx.x;
    const int lane = tid & 63, wv = tid >> 6;

    __shared__ double ssum[4];
    __shared__ float  smax[4];
    __shared__ float  sh_inv;
    __shared__ float  sh_thresh;

    // ---------------- Phase A: w partial abs-sum ----------------
    {
        double lsum = 0.0;
        const float4* w4 = (const float4*)w;
        for (int i = bid * 256 + tid; i < OUT_F * IN_F / 4; i += NPART * 256) {
            float4 v = w4[i];
            lsum += (double)fabsf(v.x) + (double)fabsf(v.y) +
                    (double)fabsf(v.z) + (double)fabsf(v.w);
        }
        for (int off = 32; off > 0; off >>= 1) lsum += __shfl_down(lsum, off, 64);
        if (lane == 0) ssum[wv] = lsum;
        __syncthreads();
        if (tid == 0) {
            g_wsum_p[bid] = ssum[0] + ssum[1] + ssum[2] + ssum[3];
            __threadfence();   // partial visible before the counter bump
            __hip_atomic_fetch_add(&g_done, 1u, __ATOMIC_RELEASE,
                                   __HIP_MEMORY_SCOPE_AGENT);
        }
    }

    // ---------------- Phase B: x per-row quantization (4 rows) ----------------
    for (int r = 0; r < 4; ++r) {
        const int row = bid * 4 + r;
        const float4* x4 = (const float4*)(x + (size_t)row * IN_F);

        float4 v[4];
        float lmax = 0.f;
#pragma unroll
        for (int j = 0; j < 4; ++j) {
            v[j] = x4[tid + j * 256];                  // coalesced
            lmax = fmaxf(lmax, fmaxf(fmaxf(fabsf(v[j].x), fabsf(v[j].y)),
                                     fmaxf(fabsf(v[j].z), fabsf(v[j].w))));
        }
        for (int off = 32; off > 0; off >>= 1)
            lmax = fmaxf(lmax, __shfl_down(lmax, off, 64));
        if (lane == 0) smax[wv] = lmax;
        __syncthreads();
        if (tid == 0) {
            float m = fmaxf(fmaxf(smax[0], smax[1]), fmaxf(smax[2], smax[3]));
            g_sx[row] = m * (1.f / 127.f);
            sh_inv = m > 0.f ? 127.f / m : 0.f;
        }
        __syncthreads();
        const float inv = sh_inv;

        signed char q[16];
#pragma unroll
        for (int j = 0; j < 4; ++j) {
            q[4*j+0] = (signed char)(int)rintf(fminf(fmaxf(v[j].x * inv, -127.f), 127.f));
            q[4*j+1] = (signed char)(int)rintf(fminf(fmaxf(v[j].y * inv, -127.f), 127.f));
            q[4*j+2] = (signed char)(int)rintf(fminf(fmaxf(v[j].z * inv, -127.f), 127.f));
            q[4*j+3] = (signed char)(int)rintf(fminf(fmaxf(v[j].w * inv, -127.f), 127.f));
        }
        i32x4 val; __builtin_memcpy(&val, q, 16);
        // store layout: thread tid owns bytes [tid*16, tid*16+16) of the row,
        // matching the q packing from v[j] = floats [tid*16/4 + j*... ]
        // NOTE: v[j] holds floats at element tid*4 + j*1024; pack accordingly:
        // we instead store each float4's 4 bytes to its own slot below.
        ((int*)(g_xq + (size_t)row * IN_F))[tid + 0 * 256] = ((int*)q)[0];
        ((int*)(g_xq + (size_t)row * IN_F))[tid + 1 * 256] = ((int*)q)[1];
        ((int*)(g_xq + (size_t)row * IN_F))[tid + 2 * 256] = ((int*)q)[2];
        ((int*)(g_xq + (size_t)row * IN_F))[tid + 3 * 256] = ((int*)q)[3];
        (void)val;
    }

    // ---------------- Phase C: wait for all phase-A publications ----------------
    if (tid == 0) {
        while (__hip_atomic_load(&g_done, __ATOMIC_ACQUIRE,
                                 __HIP_MEMORY_SCOPE_AGENT) < (unsigned)NPART)
            __builtin_amdgcn_s_sleep(2);
    }
    __syncthreads();   // acquire + cache-inv ordered before phase-D loads

    // ---------------- Phase D: threshold + w ternarization ----------------
    {
        double s = 0.0;
        for (int i = tid; i < NPART; i += 256) s += g_wsum_p[i];
        for (int off = 32; off > 0; off >>= 1) s += __shfl_down(s, off, 64);
        if (lane == 0) ssum[wv] = s;
        __syncthreads();
        if (tid == 0) {
            double tot = ssum[0] + ssum[1] + ssum[2] + ssum[3];
            sh_thresh = (float)(0.5 * tot / (double)((size_t)OUT_F * IN_F));
        }
        __syncthreads();
        const float thresh = sh_thresh;

        const float4* w4 = (const float4*)w;
        i32x4* wout = (i32x4*)g_wq;
        for (int i = bid * 256 + tid; i < OUT_F * IN_F / 16; i += NPART * 256) {
            signed char q[16];
#pragma unroll
            for (int j = 0; j < 4; ++j) {
                float4 v = w4[i * 4 + j];
                q[4*j+0] = v.x > thresh ? 1 : (v.x < -thresh ? -1 : 0);
                q[4*j+1] = v.y > thresh ? 1 : (v.y < -thresh ? -1 : 0);
                q[4*j+2] = v.z > thresh ? 1 : (v.z < -thresh ? -1 : 0);
                q[4*j+3] = v.w > thresh ? 1 : (v.w < -thresh ? -1 : 0);
            }
            i32x4 val; __builtin_memcpy(&val, q, 16);
            wout[i] = val;
        }
    }

    // ---------------- self-reset of counters (last finisher) ----------------
    if (tid == 0) {
        unsigned old = __hip_atomic_fetch_add(&g_fin, 1u, __ATOMIC_ACQ_REL,
                                              __HIP_MEMORY_SCOPE_AGENT);
        if (old == (unsigned)NPART - 1) {
            // all blocks are past phase C and past their g_fin bump
            __hip_atomic_store(&g_done, 0u, __ATOMIC_RELAXED, __HIP_MEMORY_SCOPE_AGENT);
            __hip_atomic_store(&g_fin,  0u, __ATOMIC_RELAXED, __HIP_MEMORY_SCOPE_AGENT);
        }
    }
}

// ---------------------------------------------------------------------------
// Kernel 2: i8 GEMM, 256x256 tile, BK=128 bytes, 8 waves (2M x 4N), double-
// buffered 128 KiB LDS, counted vmcnt(8) pipeline, XOR bank-swizzle
// (row&7)<<4 applied as inverse-permuted global source + swizzled ds_read
// address, setprio around MFMA clusters.
//
// Barriers are `asm volatile("s_barrier":::"memory")` — memory clobber pins
// C-level LDS reads below / staging above (raw builtin allows hoisting =>
// race, seen round 2). No vmcnt(0) drain in main loop.
//
// Round 5: XCD swizzle REVERTED (round-4 A/B: 164->180 µs, FETCH unchanged —
// default round-robin dispatch already gives each XCD a ~2 MiB B working set
// that fits its 4 MiB L2; chunked swizzle blew it to 16 MiB).
// ---------------------------------------------------------------------------
#define GLD_LDS(gp, lp) \
    __builtin_amdgcn_global_load_lds( \
        (const __attribute__((address_space(1))) void*)(gp), \
        (__attribute__((address_space(3))) void*)(lp), 16, 0, 0)

__global__ __launch_bounds__(512, 2) void tl_gemm_i8(
    const float* __restrict__ bias,
    const float* __restrict__ gamma_p,
    float* __restrict__ C) {
    constexpr int K = IN_F, N = OUT_F;
    constexpr int BKB = 128;            // K-bytes per tile
    constexpr int KT  = K / BKB;        // 32 K-tiles

    __shared__ __align__(16) signed char lds[2 * 65536];   // 128 KiB

    const int tid  = threadIdx.x;
    const int lane = tid & 63;
    const int wave = tid >> 6;
    const int wm   = (wave >> 2) * 128;   // 0 / 128
    const int wn   = (wave & 3) * 64;     // 0 / 64 / 128 / 192
    const int rowBase = blockIdx.y * 256; // M
    const int colBase = blockIdx.x * 256; // N

    // ---- staging source pointers (inverse-swizzled global addresses) ----
    // LDS chunk c: row = c>>3, stored col16 = c&7. It holds the logical
    // element at col16 ^ (row&7)  (XOR swizzle is an involution).
    const signed char* Asrc[4];
    const signed char* Bsrc[4];
#pragma unroll
    for (int j = 0; j < 4; ++j) {
        const int c   = j * 512 + tid;
        const int row = c >> 3;
        const int col = ((c & 7) ^ (row & 7)) * 16;
        Asrc[j] = g_xq + (size_t)(rowBase + row) * K + col;
        Bsrc[j] = g_wq + (size_t)(colBase + row) * K + col;
    }
    char* ldsp = (char*)lds;
    const int stgOff = wave * 1024;       // wave-uniform dest within 8 KiB group

    i32x4 acc[8][4] = {};

    const int r16 = lane & 15;
    const int kq  = (lane >> 4) * 16;
    const int sxz = (lane & 7) << 4;      // read-side swizzle: row&7 == lane&7

    // ---- prologue: stage tiles 0 (buf0) and 1 (buf1) ----
#pragma unroll
    for (int b = 0; b < 2; ++b) {
#pragma unroll
        for (int j = 0; j < 4; ++j)
            GLD_LDS(Asrc[j] + b * BKB, ldsp + b * 65536 + j * 8192 + stgOff);
#pragma unroll
        for (int j = 0; j < 4; ++j)
            GLD_LDS(Bsrc[j] + b * BKB, ldsp + b * 65536 + 32768 + j * 8192 + stgOff);
    }

#define TILE_BODY(VMC, BUFB, DO_STAGE, TNEXT)                                 \
    {                                                                         \
        asm volatile("s_waitcnt vmcnt(" #VMC ")" ::: "memory");               \
        asm volatile("s_barrier" ::: "memory");                               \
        const char* pA = ldsp + (BUFB) * 65536 + (wm + r16) * BKB;            \
        const char* pB = ldsp + (BUFB) * 65536 + 32768 + (wn + r16) * BKB;    \
        i32x4 af[8], bf[4];                                                   \
        _Pragma("unroll")                                                     \
        for (int kk = 0; kk < 2; ++kk) {                                      \
            const int cp = (kq + kk * 64) ^ sxz;                              \
            _Pragma("unroll")                                                 \
            for (int im = 0; im < 8; ++im)                                    \
                af[im] = *(const i32x4*)(pA + im * 2048 + cp);                \
            _Pragma("unroll")                                                 \
            for (int in = 0; in < 4; ++in)                                    \
                bf[in] = *(const i32x4*)(pB + in * 2048 + cp);                \
            __builtin_amdgcn_s_setprio(1);                                    \
            _Pragma("unroll")                                                 \
            for (int im = 0; im < 8; ++im)                                    \
                _Pragma("unroll")                                             \
                for (int in = 0; in < 4; ++in)                                \
                    acc[im][in] = __builtin_amdgcn_mfma_i32_16x16x64_i8(      \
                        af[im], bf[in], acc[im][in], 0, 0, 0);                \
            __builtin_amdgcn_s_setprio(0);                                    \
        }                                                                     \
        asm volatile("s_waitcnt lgkmcnt(0)" ::: "memory");                    \
        __builtin_amdgcn_sched_barrier(0);                                    \
        asm volatile("s_barrier" ::: "memory");                               \
        if (DO_STAGE) {                                                       \
            _Pragma("unroll")                                                 \
            for (int j = 0; j < 4; ++j)                                       \
                GLD_LDS(Asrc[j] + (TNEXT) * BKB,                              \
                        ldsp + (BUFB) * 65536 + j * 8192 + stgOff);           \
            _Pragma("unroll")                                                 \
            for (int j = 0; j < 4; ++j)                                       \
                GLD_LDS(Bsrc[j] + (TNEXT) * BKB,                              \
                        ldsp + (BUFB) * 65536 + 32768 + j * 8192 + stgOff);   \
        }                                                                     \
    }

    for (int t = 0; t < KT - 2; t += 2) {
        TILE_BODY(8, 0, true, t + 2)
        TILE_BODY(8, 1, true, t + 3)
    }
    TILE_BODY(8, 0, false, 0)
    TILE_BODY(0, 1, false, 0)
#undef TILE_BODY

    // Epilogue. C/D layout: col = lane&15, row = (lane>>4)*4 + reg.
    const float g  = *gamma_p;
    const int cq = (lane >> 4) * 4;
    int   bcol[4];
    float bg[4];
#pragma unroll
    for (int in = 0; in < 4; ++in) {
        bcol[in] = colBase + wn + in * 16 + r16;
        bg[in]   = bias[bcol[in]] * g;
    }
#pragma unroll
    for (int im = 0; im < 8; ++im) {
        const int rowb = rowBase + wm + im * 16 + cq;
        float sg[4];
#pragma unroll
        for (int r = 0; r < 4; ++r) sg[r] = g_sx[rowb + r] * g;
#pragma unroll
        for (int in = 0; in < 4; ++in)
#pragma unroll
            for (int r = 0; r < 4; ++r)
                C[(size_t)(rowb + r) * N + bcol[in]] =
                    (float)acc[im][in][r] * sg[r] + bg[in];
    }
}

// ---------------------------------------------------------------------------
// Launch: 2 kernels. No d_ws usage.
// ---------------------------------------------------------------------------
extern "C" void kernel_launch(void* const* d_in, const int* in_sizes, int n_in,
                              void* d_out, int out_size, void* d_ws, size_t ws_size,
                              hipStream_t stream) {
    const float* x     = (const float*)d_in[0];
    const float* w     = (const float*)d_in[1];
    const float* bias  = (const float*)d_in[2];
    const float* gamma = (const float*)d_in[3];
    float* out = (float*)d_out;
    (void)d_ws; (void)ws_size;

    tl_prep<<<NPART, 256, 0, stream>>>(x, w);

    dim3 grid(OUT_F / 256, NROWS / 256);
    tl_gemm_i8<<<grid, 512, 0, stream>>>(bias, gamma, out);
}

// Round 6
// 434.033 us; speedup vs baseline: 1.6493x; 1.6493x over previous
//
#include <hip/hip_runtime.h>

// Problem constants
#define NROWS 8192   // rows of x / out
#define IN_F  4096   // K
#define OUT_F 4096   // output features
#define NPART 2048   // partial slots for w stats

typedef __attribute__((ext_vector_type(4))) int i32x4;

// ---------------------------------------------------------------------------
// Static device scratch. Fully rewritten on every kernel_launch call.
// NO device-scope fences/atomics anywhere (round-5 lesson: agent-scope
// release/acquire protocol cost 4x on streaming throughput).
// ---------------------------------------------------------------------------
__device__ double g_wsum_p[NPART];                  // per-block sum|w| (fp64)
__device__ float  g_sx[NROWS];                      // per-row x scale = rowmax/127
__device__ signed char g_wq[(size_t)OUT_F * IN_F];  // 16 MiB ternary i8
__device__ signed char g_xq[(size_t)NROWS * IN_F];  // 32 MiB x in i8

// ---------------------------------------------------------------------------
// Kernel 1: w stats pass — sum|w| (fp64), per-block partials. No atomics.
// ---------------------------------------------------------------------------
__global__ __launch_bounds__(256) void tl_wstats(const float* __restrict__ w) {
    const int idx = blockIdx.x * blockDim.x + threadIdx.x;
    const int stride = gridDim.x * blockDim.x;

    double lsum = 0.0;
    const float4* w4 = (const float4*)w;
    for (int i = idx; i < OUT_F * IN_F / 4; i += stride) {
        float4 v = w4[i];
        lsum += (double)fabsf(v.x) + (double)fabsf(v.y) +
                (double)fabsf(v.z) + (double)fabsf(v.w);
    }
    for (int off = 32; off > 0; off >>= 1) lsum += __shfl_down(lsum, off, 64);
    __shared__ double ssum[4];
    int lane = threadIdx.x & 63, wv = threadIdx.x >> 6;
    if (lane == 0) ssum[wv] = lsum;
    __syncthreads();
    if (threadIdx.x == 0)
        g_wsum_p[blockIdx.x] = ssum[0] + ssum[1] + ssum[2] + ssum[3];
}

// ---------------------------------------------------------------------------
// Kernel 2: finalize w stats (per-block recompute from L2-resident partials),
// then quantize w -> ternary i8 (16 elements / thread / iter, 16 B stores).
// ---------------------------------------------------------------------------
__global__ __launch_bounds__(256) void tl_wquant(const float* __restrict__ w) {
    double s = 0.0;
    for (int i = threadIdx.x; i < NPART; i += 256) s += g_wsum_p[i];
    for (int off = 32; off > 0; off >>= 1) s += __shfl_down(s, off, 64);
    __shared__ double ssum[4];
    __shared__ float sh_thresh;
    int lane = threadIdx.x & 63, wv = threadIdx.x >> 6;
    if (lane == 0) ssum[wv] = s;
    __syncthreads();
    if (threadIdx.x == 0) {
        double tot = ssum[0] + ssum[1] + ssum[2] + ssum[3];
        sh_thresh = (float)(0.5 * tot / (double)((size_t)OUT_F * IN_F));
    }
    __syncthreads();
    const float thresh = sh_thresh;

    const int idx = blockIdx.x * blockDim.x + threadIdx.x;
    const int stride = gridDim.x * blockDim.x;

    const float4* w4 = (const float4*)w;
    i32x4* wout = (i32x4*)g_wq;
    for (int i = idx; i < OUT_F * IN_F / 16; i += stride) {
        signed char q[16];
#pragma unroll
        for (int j = 0; j < 4; ++j) {
            float4 v = w4[i * 4 + j];
            q[4*j+0] = v.x > thresh ? 1 : (v.x < -thresh ? -1 : 0);
            q[4*j+1] = v.y > thresh ? 1 : (v.y < -thresh ? -1 : 0);
            q[4*j+2] = v.z > thresh ? 1 : (v.z < -thresh ? -1 : 0);
            q[4*j+3] = v.w > thresh ? 1 : (v.w < -thresh ? -1 : 0);
        }
        i32x4 val; __builtin_memcpy(&val, q, 16);
        wout[i] = val;
    }
}

// ---------------------------------------------------------------------------
// Kernel 3: x per-row quantization, SINGLE PASS (row held in registers).
// scale_m = rowmax/127 factors out of the integer dot product exactly.
// ---------------------------------------------------------------------------
__global__ __launch_bounds__(256) void tl_xquant(const float* __restrict__ x) {
    const int row = blockIdx.x;
    const int tid = threadIdx.x;
    const float4* x4 = (const float4*)(x + (size_t)row * IN_F);

    float4 v[4];
    float lmax = 0.f;
#pragma unroll
    for (int j = 0; j < 4; ++j) {
        v[j] = x4[tid + j * 256];
        lmax = fmaxf(lmax, fmaxf(fmaxf(fabsf(v[j].x), fabsf(v[j].y)),
                                 fmaxf(fabsf(v[j].z), fabsf(v[j].w))));
    }
    for (int off = 32; off > 0; off >>= 1)
        lmax = fmaxf(lmax, __shfl_down(lmax, off, 64));
    __shared__ float smax[4];
    __shared__ float sh_inv;
    int lane = tid & 63, wv = tid >> 6;
    if (lane == 0) smax[wv] = lmax;
    __syncthreads();
    if (tid == 0) {
        float m = fmaxf(fmaxf(smax[0], smax[1]), fmaxf(smax[2], smax[3]));
        g_sx[row] = m * (1.f / 127.f);
        sh_inv = m > 0.f ? 127.f / m : 0.f;
    }
    __syncthreads();
    const float inv = sh_inv;

    int* xout = (int*)(g_xq + (size_t)row * IN_F);
#pragma unroll
    for (int j = 0; j < 4; ++j) {
        signed char q[4];
        q[0] = (signed char)(int)rintf(fminf(fmaxf(v[j].x * inv, -127.f), 127.f));
        q[1] = (signed char)(int)rintf(fminf(fmaxf(v[j].y * inv, -127.f), 127.f));
        q[2] = (signed char)(int)rintf(fminf(fmaxf(v[j].z * inv, -127.f), 127.f));
        q[3] = (signed char)(int)rintf(fminf(fmaxf(v[j].w * inv, -127.f), 127.f));
        int val; __builtin_memcpy(&val, q, 4);
        xout[tid + j * 256] = val;
    }
}

// ---------------------------------------------------------------------------
// Kernel 4: i8 GEMM, 256x256 tile, BK=128 bytes, 8 waves (2M x 4N), double-
// buffered 128 KiB LDS, counted vmcnt(8), XOR bank-swizzle (both-sides),
// NO XCD swizzle (round-4 A/B: hurt).
//
// Round 6: 4-SUB-PHASE per K-tile (m201 skeleton). Each phase:
//   [ds_reads -> s_barrier -> lgkmcnt(0) -> sched_barrier -> setprio(1)
//    -> 16 MFMA -> setprio(0) -> s_barrier]
// bf fragments are loaded once per kk and reused across the two m-half
// phases (24 ds_read_b128 per tile, no redundancy). Staging stays at tile
// end (earliest safe point in a 2-buffer scheme: in-flight global_load_lds
// always writes the buffer NOT being read, so the sub-phases introduce no
// new write-while-read window). All barriers are asm volatile with memory
// clobber (round-2 race lesson: the builtin allows ds_read hoisting).
// ---------------------------------------------------------------------------
#define GLD_LDS(gp, lp) \
    __builtin_amdgcn_global_load_lds( \
        (const __attribute__((address_space(1))) void*)(gp), \
        (__attribute__((address_space(3))) void*)(lp), 16, 0, 0)

__global__ __launch_bounds__(512, 2) void tl_gemm_i8(
    const float* __restrict__ bias,
    const float* __restrict__ gamma_p,
    float* __restrict__ C) {
    constexpr int K = IN_F, N = OUT_F;
    constexpr int BKB = 128;            // K-bytes per tile
    constexpr int KT  = K / BKB;        // 32 K-tiles

    __shared__ __align__(16) signed char lds[2 * 65536];   // 128 KiB

    const int tid  = threadIdx.x;
    const int lane = tid & 63;
    const int wave = tid >> 6;
    const int wm   = (wave >> 2) * 128;   // 0 / 128
    const int wn   = (wave & 3) * 64;     // 0 / 64 / 128 / 192
    const int rowBase = blockIdx.y * 256; // M
    const int colBase = blockIdx.x * 256; // N

    // ---- staging source pointers (inverse-swizzled global addresses) ----
    // LDS chunk c: row = c>>3, stored col16 = c&7. It holds the logical
    // element at col16 ^ (row&7)  (XOR swizzle is an involution).
    const signed char* Asrc[4];
    const signed char* Bsrc[4];
#pragma unroll
    for (int j = 0; j < 4; ++j) {
        const int c   = j * 512 + tid;
        const int row = c >> 3;
        const int col = ((c & 7) ^ (row & 7)) * 16;
        Asrc[j] = g_xq + (size_t)(rowBase + row) * K + col;
        Bsrc[j] = g_wq + (size_t)(colBase + row) * K + col;
    }
    char* ldsp = (char*)lds;
    const int stgOff = wave * 1024;       // wave-uniform dest within 8 KiB group

    i32x4 acc[8][4] = {};

    const int r16 = lane & 15;
    const int kq  = (lane >> 4) * 16;
    const int sxz = (lane & 7) << 4;      // read-side swizzle: row&7 == lane&7

    // ---- prologue: stage tiles 0 (buf0) and 1 (buf1) ----
#pragma unroll
    for (int b = 0; b < 2; ++b) {
#pragma unroll
        for (int j = 0; j < 4; ++j)
            GLD_LDS(Asrc[j] + b * BKB, ldsp + b * 65536 + j * 8192 + stgOff);
#pragma unroll
        for (int j = 0; j < 4; ++j)
            GLD_LDS(Bsrc[j] + b * BKB, ldsp + b * 65536 + 32768 + j * 8192 + stgOff);
    }

    // One sub-phase: ds_reads already issued by caller; sync, wait, MFMA.
#define PHASE_TAIL()                                                          \
        asm volatile("s_barrier" ::: "memory");                               \
        asm volatile("s_waitcnt lgkmcnt(0)" ::: "memory");                    \
        __builtin_amdgcn_sched_barrier(0);                                    \
        __builtin_amdgcn_s_setprio(1);

#define PHASE_END()                                                           \
        __builtin_amdgcn_s_setprio(0);                                        \
        asm volatile("s_barrier" ::: "memory");

#define TILE_BODY(VMC, BUFB, DO_STAGE, TNEXT)                                 \
    {                                                                         \
        asm volatile("s_waitcnt vmcnt(" #VMC ")" ::: "memory");               \
        asm volatile("s_barrier" ::: "memory");                               \
        const char* pA = ldsp + (BUFB) * 65536 + (wm + r16) * BKB;            \
        const char* pB = ldsp + (BUFB) * 65536 + 32768 + (wn + r16) * BKB;    \
        i32x4 af[4], bf[4];                                                   \
        const int cp0 = kq ^ sxz;                                             \
        const int cp1 = (kq + 64) ^ sxz;                                      \
        /* ---- P0: kk=0, m-frags 0..3 (reads af+bf) ---- */                  \
        _Pragma("unroll")                                                     \
        for (int im = 0; im < 4; ++im)                                        \
            af[im] = *(const i32x4*)(pA + im * 2048 + cp0);                   \
        _Pragma("unroll")                                                     \
        for (int in = 0; in < 4; ++in)                                        \
            bf[in] = *(const i32x4*)(pB + in * 2048 + cp0);                   \
        PHASE_TAIL()                                                          \
        _Pragma("unroll")                                                     \
        for (int im = 0; im < 4; ++im)                                        \
            _Pragma("unroll")                                                 \
            for (int in = 0; in < 4; ++in)                                    \
                acc[im][in] = __builtin_amdgcn_mfma_i32_16x16x64_i8(          \
                    af[im], bf[in], acc[im][in], 0, 0, 0);                    \
        PHASE_END()                                                           \
        /* ---- P1: kk=0, m-frags 4..7 (reuse bf) ---- */                     \
        _Pragma("unroll")                                                     \
        for (int im = 0; im < 4; ++im)                                        \
            af[im] = *(const i32x4*)(pA + (im + 4) * 2048 + cp0);             \
        PHASE_TAIL()                                                          \
        _Pragma("unroll")                                                     \
        for (int im = 0; im < 4; ++im)                                        \
            _Pragma("unroll")                                                 \
            for (int in = 0; in < 4; ++in)                                    \
                acc[im + 4][in] = __builtin_amdgcn_mfma_i32_16x16x64_i8(      \
                    af[im], bf[in], acc[im + 4][in], 0, 0, 0);                \
        PHASE_END()                                                           \
        /* ---- P2: kk=1, m-frags 0..3 (reads af+bf) ---- */                  \
        _Pragma("unroll")                                                     \
        for (int im = 0; im < 4; ++im)                                        \
            af[im] = *(const i32x4*)(pA + im * 2048 + cp1);                   \
        _Pragma("unroll")                                                     \
        for (int in = 0; in < 4; ++in)                                        \
            bf[in] = *(const i32x4*)(pB + in * 2048 + cp1);                   \
        PHASE_TAIL()                                                          \
        _Pragma("unroll")                                                     \
        for (int im = 0; im < 4; ++im)                                        \
            _Pragma("unroll")                                                 \
            for (int in = 0; in < 4; ++in)                                    \
                acc[im][in] = __builtin_amdgcn_mfma_i32_16x16x64_i8(          \
                    af[im], bf[in], acc[im][in], 0, 0, 0);                    \
        PHASE_END()                                                           \
        /* ---- P3: kk=1, m-frags 4..7 (reuse bf) ---- */                     \
        _Pragma("unroll")                                                     \
        for (int im = 0; im < 4; ++im)                                        \
            af[im] = *(const i32x4*)(pA + (im + 4) * 2048 + cp1);             \
        PHASE_TAIL()                                                          \
        _Pragma("unroll")                                                     \
        for (int im = 0; im < 4; ++im)                                        \
            _Pragma("unroll")                                                 \
            for (int in = 0; in < 4; ++in)                                    \
                acc[im + 4][in] = __builtin_amdgcn_mfma_i32_16x16x64_i8(      \
                    af[im], bf[in], acc[im + 4][in], 0, 0, 0);                \
        PHASE_END()                                                           \
        /* after P3's barrier: all waves done reading buf -> stage into it */ \
        if (DO_STAGE) {                                                       \
            _Pragma("unroll")                                                 \
            for (int j = 0; j < 4; ++j)                                       \
                GLD_LDS(Asrc[j] + (TNEXT) * BKB,                              \
                        ldsp + (BUFB) * 65536 + j * 8192 + stgOff);           \
            _Pragma("unroll")                                                 \
            for (int j = 0; j < 4; ++j)                                       \
                GLD_LDS(Bsrc[j] + (TNEXT) * BKB,                              \
                        ldsp + (BUFB) * 65536 + 32768 + j * 8192 + stgOff);   \
        }                                                                     \
    }

    for (int t = 0; t < KT - 2; t += 2) {
        TILE_BODY(8, 0, true, t + 2)
        TILE_BODY(8, 1, true, t + 3)
    }
    TILE_BODY(8, 0, false, 0)
    TILE_BODY(0, 1, false, 0)
#undef TILE_BODY
#undef PHASE_TAIL
#undef PHASE_END

    // Epilogue. C/D layout: col = lane&15, row = (lane>>4)*4 + reg.
    const float g  = *gamma_p;
    const int cq = (lane >> 4) * 4;
    int   bcol[4];
    float bg[4];
#pragma unroll
    for (int in = 0; in < 4; ++in) {
        bcol[in] = colBase + wn + in * 16 + r16;
        bg[in]   = bias[bcol[in]] * g;
    }
#pragma unroll
    for (int im = 0; im < 8; ++im) {
        const int rowb = rowBase + wm + im * 16 + cq;
        float sg[4];
#pragma unroll
        for (int r = 0; r < 4; ++r) sg[r] = g_sx[rowb + r] * g;
#pragma unroll
        for (int in = 0; in < 4; ++in)
#pragma unroll
            for (int r = 0; r < 4; ++r)
                C[(size_t)(rowb + r) * N + bcol[in]] =
                    (float)acc[im][in][r] * sg[r] + bg[in];
    }
}

// ---------------------------------------------------------------------------
// Launch: 4 kernels. No d_ws usage.
// ---------------------------------------------------------------------------
extern "C" void kernel_launch(void* const* d_in, const int* in_sizes, int n_in,
                              void* d_out, int out_size, void* d_ws, size_t ws_size,
                              hipStream_t stream) {
    const float* x     = (const float*)d_in[0];
    const float* w     = (const float*)d_in[1];
    const float* bias  = (const float*)d_in[2];
    const float* gamma = (const float*)d_in[3];
    float* out = (float*)d_out;
    (void)d_ws; (void)ws_size;

    tl_wstats<<<NPART, 256, 0, stream>>>(w);
    tl_wquant<<<NPART, 256, 0, stream>>>(w);
    tl_xquant<<<NROWS, 256, 0, stream>>>(x);

    dim3 grid(OUT_F / 256, NROWS / 256);
    tl_gemm_i8<<<grid, 512, 0, stream>>>(bias, gamma, out);
}